// Round 5
// baseline (607.067 us; speedup 1.0000x reference)
//
#include <hip/hip_runtime.h>
#include <stdint.h>
#include <stddef.h>

// ---------------- problem constants ----------------
#define N_NODES  4096
#define N_EDGES  12288
#define EA_EDGES 16384      // N_EDGES + N_NODES self loops
#define NBATCH   64
#define CLIPD    768
#define HIDD     1024
#define C2D      3072
#define NEG_SLOPE 0.2f
#define MAXDEG   96         // in-degree ~Poisson(3); P(>96) ~ 0

typedef unsigned short u16;
typedef short bf16x8 __attribute__((ext_vector_type(8)));   // 8 bf16 = 4 VGPRs (guide §3)
typedef float f32x4  __attribute__((ext_vector_type(4)));

static __device__ __forceinline__ float b2f(u16 u) {
    union { float f; unsigned int i; } v; v.i = ((unsigned int)u) << 16; return v.f;
}
static __device__ __forceinline__ u16 f2b(float f) {
    union { float f; unsigned int i; } v; v.f = f;
    unsigned int r = (v.i + 0x7fffu + ((v.i >> 16) & 1u)) >> 16;   // RNE
    return (u16)r;
}
// dtype-polymorphic 4-element vector load (fp32 or bf16 source) -> 4 floats
static __device__ __forceinline__ void ld4(const float* p, float v[4]) {
    float4 t = *(const float4*)p;
    v[0] = t.x; v[1] = t.y; v[2] = t.z; v[3] = t.w;
}
static __device__ __forceinline__ void ld4(const u16* p, float v[4]) {
    ushort4 t = *(const ushort4*)p;
    v[0] = b2f(t.x); v[1] = b2f(t.y); v[2] = b2f(t.z); v[3] = b2f(t.w);
}

static __device__ __forceinline__ float wsum(float v) {
#pragma unroll
    for (int o = 32; o > 0; o >>= 1) v += __shfl_xor(v, o, 64);
    return v;
}
static __device__ __forceinline__ float wmax(float v) {
#pragma unroll
    for (int o = 32; o > 0; o >>= 1) v = fmaxf(v, __shfl_xor(v, o, 64));
    return v;
}
static __device__ __forceinline__ int lower_bound(const int* a, int n, int key) {
    int lo = 0, hi = n;
    while (lo < hi) { int m = (lo + hi) >> 1; if (a[m] < key) lo = m + 1; else hi = m; }
    return lo;
}

// async global->LDS, 16B per lane. LDS dst is wave-uniform base + lane*16 (m104/m108);
// our LDS offsets are exactly tid*16, satisfying that constraint.
#define GLD16(gp, lp)                                                            \
    __builtin_amdgcn_global_load_lds((const __attribute__((address_space(1))) void*)(gp), \
                                     (__attribute__((address_space(3))) void*)(lp), 16, 0, 0)

// ---------------- CSR build ----------------
__global__ void k_deg(const int* __restrict__ dst, int* __restrict__ deg) {
    int e = blockIdx.x * 256 + threadIdx.x;
    if (e < N_EDGES) atomicAdd(&deg[dst[e]], 1);
}

__global__ void k_scan(const int* __restrict__ deg, int* __restrict__ offs) {
    __shared__ int s[1024];
    int t = threadIdx.x;
    int v[4]; int sum = 0;
#pragma unroll
    for (int i = 0; i < 4; i++) { v[i] = deg[t * 4 + i] + 1; sum += v[i]; }
    s[t] = sum; __syncthreads();
    for (int st = 1; st < 1024; st <<= 1) {
        int x = 0;
        if (t >= st) x = s[t - st];
        __syncthreads();
        s[t] += x;
        __syncthreads();
    }
    int run = s[t] - sum;
#pragma unroll
    for (int i = 0; i < 4; i++) { offs[t * 4 + i] = run; run += v[i]; }
    if (t == 1023) offs[N_NODES] = run;
}

__global__ void k_fill(const int* __restrict__ dst, const int* __restrict__ offs,
                       int* __restrict__ cur, int* __restrict__ csr) {
    int id = blockIdx.x * 256 + threadIdx.x;
    if (id >= EA_EDGES) return;
    int d = (id < N_EDGES) ? dst[id] : (id - N_EDGES);
    int p = atomicAdd(&cur[d], 1);
    csr[offs[d] + p] = id;
}

// ---------------- weight-side attention reductions (fp32 in, fp32 out) ----------------
static __device__ void reduce_w_body(const float* __restrict__ W, const float* __restrict__ attA,
                                     const float* __restrict__ attB, float* __restrict__ out,
                                     int C, int col0, int d) {
    int t = threadIdx.x;
    float acc[8] = {0, 0, 0, 0, 0, 0, 0, 0};
    for (int c = t * 4; c < C; c += 1024) {
#pragma unroll
        for (int h = 0; h < 4; h++) {
            float4 w = *(const float4*)&W[((size_t)d * 4 + h) * C + c];
            float4 a = *(const float4*)&attA[h * C + c];
            acc[h] += w.x * a.x + w.y * a.y + w.z * a.z + w.w * a.w;
            if (attB) {
                float4 bv = *(const float4*)&attB[h * C + c];
                acc[4 + h] += w.x * bv.x + w.y * bv.y + w.z * bv.z + w.w * bv.w;
            }
        }
    }
    __shared__ float red[4][8];
    int lane = t & 63, wv = t >> 6;
#pragma unroll
    for (int j = 0; j < 8; j++) acc[j] = wsum(acc[j]);
    if (lane == 0) {
#pragma unroll
        for (int j = 0; j < 8; j++) red[wv][j] = acc[j];
    }
    __syncthreads();
    if (t < 8) {
        float s = red[0][t] + red[1][t] + red[2][t] + red[3][t];
        if (attB) out[d * 8 + col0 + t] = s;
        else if (t < 4) out[d * 8 + col0 + t] = s;
    }
}

// full version (fallback path): all four reductions
__global__ void k_reduce_all(const float* __restrict__ W1, const float* __restrict__ as1,
                             const float* __restrict__ ad1, float* __restrict__ vsd1,
                             const float* __restrict__ We1, const float* __restrict__ ae1,
                             const float* __restrict__ W2, const float* __restrict__ as2,
                             const float* __restrict__ ad2, float* __restrict__ vsd2,
                             const float* __restrict__ We2, const float* __restrict__ ae2,
                             float* __restrict__ we12) {
    int b = blockIdx.x;
    if (b < CLIPD)                   reduce_w_body(W1, as1, ad1, vsd1, HIDD, 0, b);
    else if (b < 2 * CLIPD)          reduce_w_body(We1, ae1, nullptr, we12, HIDD, 0, b - CLIPD);
    else if (b < 2 * CLIPD + HIDD)   reduce_w_body(W2, as2, ad2, vsd2, C2D, 0, b - 2 * CLIPD);
    else                             reduce_w_body(We2, ae2, nullptr, we12, C2D, 4, b - 2 * CLIPD - HIDD);
}

// R5 (fused path): We-only reductions -- W1/W2 reductions fold into the transpose pass
__global__ void k_reduce_we(const float* __restrict__ We1, const float* __restrict__ ae1,
                            const float* __restrict__ We2, const float* __restrict__ ae2,
                            float* __restrict__ we12) {
    int b = blockIdx.x;
    if (b < CLIPD) reduce_w_body(We1, ae1, nullptr, we12, HIDD, 0, b);
    else           reduce_w_body(We2, ae2, nullptr, we12, C2D, 4, b - CLIPD);
}

// skinny GEMV: out[row][0..7] = X[row,:] @ Wr[:,0..7]   (one wave per row, 4-wide k)
template <typename T>
static __device__ void gemv8_body(const T* __restrict__ X, int K, const float* __restrict__ Wr,
                                  float* __restrict__ out, int row) {
    int lane = threadIdx.x & 63;
    float acc[8] = {0, 0, 0, 0, 0, 0, 0, 0};
    const T* xp = X + (size_t)row * K;
    for (int k = lane * 4; k < K; k += 256) {
        float xv[4]; ld4(xp + k, xv);
#pragma unroll
        for (int kk = 0; kk < 4; kk++) {
            const float4* w = (const float4*)(Wr + (size_t)(k + kk) * 8);
            float4 w0 = w[0], w1 = w[1];
            acc[0] += xv[kk] * w0.x; acc[1] += xv[kk] * w0.y;
            acc[2] += xv[kk] * w0.z; acc[3] += xv[kk] * w0.w;
            acc[4] += xv[kk] * w1.x; acc[5] += xv[kk] * w1.y;
            acc[6] += xv[kk] * w1.z; acc[7] += xv[kk] * w1.w;
        }
    }
#pragma unroll
    for (int j = 0; j < 8; j++) acc[j] = wsum(acc[j]);
    if (lane == 0) {
#pragma unroll
        for (int j = 0; j < 8; j++) out[(size_t)row * 8 + j] = acc[j];
    }
}

template <typename T>
__global__ void k_gemv8(const T* __restrict__ X, int K, const float* __restrict__ Wr,
                        float* __restrict__ out, int rows) {
    int row = blockIdx.x * 4 + (threadIdx.x >> 6);
    if (row < rows) gemv8_body(X, K, Wr, out, row);
}

// fused dual gemv (eattr->ae and x->asd1 are independent; one dispatch)
__global__ void k_gemv8_dual(const float* __restrict__ Xa, const float* __restrict__ Wa,
                             float* __restrict__ outA, int rowsA,
                             const float* __restrict__ Xb, const float* __restrict__ Wb,
                             float* __restrict__ outB) {
    int row = blockIdx.x * 4 + (threadIdx.x >> 6);
    if (row < rowsA) gemv8_body(Xa, CLIPD, Wa, outA, row);
    else             gemv8_body(Xb, CLIPD, Wb, outB, row - rowsA);
}

// per-dst-node attention softmax + aggregation in INPUT feature space:
// agg[n, d*4+h] = sum_e coef[e,h] * feat[src_e, d]
// self-loop logit computed in-kernel (mean of incident real edges' raw ae component).
template <typename T>
__global__ void k_attn_agg(const T* __restrict__ feat, int D,
                           const float* __restrict__ asd, const float* __restrict__ ae, int aecol,
                           const int* __restrict__ offs, const int* __restrict__ csr,
                           const int* __restrict__ src, u16* __restrict__ agg) {
    int n = blockIdx.x, t = threadIdx.x;
    __shared__ int sl[MAXDEG];
    __shared__ float cf[MAXDEG][4];
    __shared__ float er[MAXDEG][4];   // raw edge-attn component (0 for self-loop slot)
    __shared__ int sidx;
    if (t == 0) sidx = -1;
    int lo = offs[n];
    int cnt = offs[n + 1] - lo;
    if (cnt > MAXDEG) cnt = MAXDEG;
    __syncthreads();
    for (int i = t; i < cnt; i += 256) {
        int eid = csr[lo + i];
        bool slf = (eid >= N_EDGES);
        int s = slf ? n : src[eid];
        sl[i] = s;
        if (slf) sidx = i;
#pragma unroll
        for (int h = 0; h < 4; h++) {
            float aev = slf ? 0.f : ae[(size_t)eid * 8 + aecol + h];
            er[i][h] = aev;
            float al = asd[(size_t)s * 8 + h] + asd[(size_t)n * 8 + 4 + h] + aev;
            cf[i][h] = (al >= 0.f) ? al : NEG_SLOPE * al;
        }
    }
    __syncthreads();
    int wv = t >> 6, lane = t & 63;
    {   // self-loop logit: head wv, wave-parallel mean of real-edge ae
        float se = 0.f;
        for (int i = lane; i < cnt; i += 64) se += er[i][wv];
        se = wsum(se);
        if (lane == 0 && sidx >= 0) {
            float al = asd[(size_t)n * 8 + wv] + asd[(size_t)n * 8 + 4 + wv] +
                       se / (float)(cnt > 1 ? cnt - 1 : 1);
            cf[sidx][wv] = (al >= 0.f) ? al : NEG_SLOPE * al;
        }
    }
    __syncthreads();
    {   // head = wave index: all 4 waves active, shuffle-reduce softmax
        float mx = -1e30f;
        for (int i = lane; i < cnt; i += 64) mx = fmaxf(mx, cf[i][wv]);
        mx = wmax(mx);
        float ds = 0.f;
        for (int i = lane; i < cnt; i += 64) {
            float e = __expf(cf[i][wv] - mx); cf[i][wv] = e; ds += e;
        }
        ds = wsum(ds);
        float inv = 1.0f / (ds + 1e-16f);
        for (int i = lane; i < cnt; i += 64) cf[i][wv] *= inv;
    }
    __syncthreads();
    for (int d4 = t * 4; d4 < D; d4 += 1024) {
        float a[4][4] = {};                     // [dj][head]
        for (int i = 0; i < cnt; i++) {
            float4 c4 = *(const float4*)cf[i];  // 4 heads, LDS broadcast
            float v[4]; ld4(feat + (size_t)sl[i] * D + d4, v);
#pragma unroll
            for (int dj = 0; dj < 4; dj++) {
                a[dj][0] += c4.x * v[dj]; a[dj][1] += c4.y * v[dj];
                a[dj][2] += c4.z * v[dj]; a[dj][3] += c4.w * v[dj];
            }
        }
        u16* op = agg + (size_t)n * 4 * D + (size_t)d4 * 4;
#pragma unroll
        for (int dj = 0; dj < 4; dj++) {
            ushort4 pk;
            pk.x = f2b(a[dj][0]); pk.y = f2b(a[dj][1]);
            pk.z = f2b(a[dj][2]); pk.w = f2b(a[dj][3]);
            *(ushort4*)(op + dj * 4) = pk;
        }
    }
}

// ---------------- transpose + downcast (fp32 [R,C] -> bf16 [C,R]) ----------------
// ushort4 stores; LDS read tile[s4+k][j]: bank = (4*(s4+k)+j)%32 covers all residues 2x = free.
// R5: optional fused attention reduction -- row r=d*4+h is loaded entirely by wave
// (r%4) (blockDim (64,4): ty = wave id), so vsd[d*8+{h,4+h}] = wsum(elem*att) +
// one atomicAdd per row. Removes the separate W1/W2 read in k_reduce_all (63 MB).
static __device__ void transpose_body(const float* __restrict__ in, u16* __restrict__ out,
                                      int R, int C, int bx, int by,
                                      const float* __restrict__ attS,
                                      const float* __restrict__ attD,
                                      float* __restrict__ vsd) {
    __shared__ float tile[64][65];
    int tx = threadIdx.x, ty = threadIdx.y;
    int rb = by * 64, cb = bx * 64;
    float as_[4], ad_[4];
    if (attS) {
#pragma unroll
        for (int h = 0; h < 4; h++) {
            as_[h] = attS[h * C + cb + tx];
            ad_[h] = attD[h * C + cb + tx];
        }
    }
    for (int i = ty; i < 64; i += 4) {
        float v = in[(size_t)(rb + i) * C + cb + tx];
        tile[i][tx] = v;
        if (attS) {
            int r = rb + i;
            int h = r & 3;
            float ps = wsum(v * as_[h]);
            float pd = wsum(v * ad_[h]);
            if (tx == 0) {
                int d = r >> 2;
                atomicAdd(&vsd[d * 8 + h], ps);
                atomicAdd(&vsd[d * 8 + 4 + h], pd);
            }
        }
    }
    __syncthreads();
    int linear = ty * 64 + tx;
#pragma unroll
    for (int jj = 0; jj < 4; jj++) {
        int idx = linear + jj * 256;
        int j = idx >> 4, s4 = (idx & 15) * 4;
        ushort4 pk;
        pk.x = f2b(tile[s4 + 0][j]);
        pk.y = f2b(tile[s4 + 1][j]);
        pk.z = f2b(tile[s4 + 2][j]);
        pk.w = f2b(tile[s4 + 3][j]);
        *(ushort4*)(out + (size_t)(cb + j) * R + rb + s4) = pk;
    }
}

__global__ void k_transpose(const float* __restrict__ in, u16* __restrict__ out, int R, int C) {
    transpose_body(in, out, R, C, blockIdx.x, blockIdx.y, nullptr, nullptr, nullptr);
}

// all four weight transposes in ONE dispatch; W1/W2 segments also emit vsd1/vsd2.
// tiles: W1 [3072,1024]=768, W2 [4096,3072]=3072, gW1 [3072,1024]=768, gW2 [1024,1024]=256.
__global__ void k_transpose_red_all(
        const float* __restrict__ W1, u16* __restrict__ W1t,
        const float* __restrict__ as1, const float* __restrict__ ad1, float* __restrict__ vsd1,
        const float* __restrict__ W2, u16* __restrict__ W2t,
        const float* __restrict__ as2, const float* __restrict__ ad2, float* __restrict__ vsd2,
        const float* __restrict__ gW1, u16* __restrict__ gW1t,
        const float* __restrict__ gW2, u16* __restrict__ gW2t) {
    int b = blockIdx.x;
    if (b < 768) {
        transpose_body(W1, W1t, 3072, 1024, b % 16, b / 16, as1, ad1, vsd1);
    } else if (b < 3840) {
        int lb = b - 768;
        transpose_body(W2, W2t, 4096, 3072, lb % 48, lb / 48, as2, ad2, vsd2);
    } else if (b < 4608) {
        int lb = b - 3840;
        transpose_body(gW1, gW1t, 3072, 1024, lb % 16, lb / 16, nullptr, nullptr, nullptr);
    } else {
        int lb = b - 4608;
        transpose_body(gW2, gW2t, 1024, 1024, lb % 16, lb / 16, nullptr, nullptr, nullptr);
    }
}

// ---------------- MFMA GEMM: C = prelu(scale * A@Bt^T + bias) ----------------
// A [M,K] bf16 row-major, Bt [N,K] bf16 row-major. 128xBN tile, 4 waves, KSUB
// 64-wide k-subtiles per barrier pair.
// R5 lesson (R4 refuted staging-BW theory): this structure is drain-stall-bound
// and needs >=2 blocks/CU so a co-resident block covers the vmcnt(0)+barrier
// drain (m114 implicit overlap). BN=256 (384 blocks, 1.5/CU) REGRESSED 110->130;
// big GEMM stays BN=128 (768 blocks, 3/CU).
// GATE mode: dot-reduce prelu(C) against gW3, atomicAdd into gate[row].
template <int BN, int KSUB, int GATE>
static __device__ __forceinline__ void gemm_body(
        const u16* __restrict__ A, const u16* __restrict__ Bt, void* __restrict__ Cout,
        const float* __restrict__ bias, const float* __restrict__ prelu, float scale,
        int N, int K, int f32out,
        const float* __restrict__ gW3, float* __restrict__ gateOut) {
    constexpr int NJ = BN / 32;              // 16-wide n-subtiles per wave (2 waves along N)
    constexpr int NBCH = BN * 8 / 256;       // B chunks per thread per subtile
    __shared__ __align__(16) u16 As[KSUB * 128 * 64];
    __shared__ __align__(16) u16 Bs[KSUB * BN * 64];
    int tid = threadIdx.x;
    int lane = tid & 63, wv = tid >> 6;
    int gx = gridDim.x;
    int bx = blockIdx.x, by = blockIdx.y;
    if ((gx & 7) == 0) {                     // bijective when gx%8==0
        int flat = by * gx + bx;
        int nx_per = gx >> 3;
        int xcd = flat & 7, idx = flat >> 3;
        bx = xcd * nx_per + idx % nx_per;
        by = idx / nx_per;
    }
    int m0 = by * 128, n0 = bx * BN;
    const u16* agp[4]; int alo[4];
#pragma unroll
    for (int u = 0; u < 4; u++) {
        int c = tid + u * 256;
        int r = c >> 3, kb = (c & 7) ^ (r & 7);
        agp[u] = A + (size_t)(m0 + r) * K + kb * 8;
        alo[u] = c * 8;
    }
    const u16* bgp[NBCH]; int blo[NBCH];
#pragma unroll
    for (int u = 0; u < NBCH; u++) {
        int c = tid + u * 256;
        int r = c >> 3, kb = (c & 7) ^ (r & 7);
        bgp[u] = Bt + (size_t)(n0 + r) * K + kb * 8;
        blo[u] = c * 8;
    }
    int wm = wv & 1, wn = wv >> 1;
    int rl = lane & 15, q = lane >> 4;
    int swz = rl & 7;
    int mb = wm * 64 + rl;
    int nb = wn * (NJ * 16) + rl;
    f32x4 acc[4][NJ] = {};
    for (int k0 = 0; k0 < K; k0 += 64 * KSUB) {
        __syncthreads();                       // previous tile's LDS reads done
#pragma unroll
        for (int su = 0; su < KSUB; su++) {
#pragma unroll
            for (int u = 0; u < 4; u++)    GLD16(agp[u] + su * 64, As + su * (128 * 64) + alo[u]);
#pragma unroll
            for (int u = 0; u < NBCH; u++) GLD16(bgp[u] + su * 64, Bs + su * (BN * 64) + blo[u]);
        }
#pragma unroll
        for (int u = 0; u < 4; u++)    agp[u] += 64 * KSUB;
#pragma unroll
        for (int u = 0; u < NBCH; u++) bgp[u] += 64 * KSUB;
        __syncthreads();                       // drains vmcnt(0): staging landed
#pragma unroll
        for (int su = 0; su < KSUB; su++) {
            const u16* Asb = As + su * (128 * 64);
            const u16* Bsb = Bs + su * (BN * 64);
            bf16x8 af[4][2], bfr[NJ][2];
#pragma unroll
            for (int i = 0; i < 4; i++)
#pragma unroll
                for (int s = 0; s < 2; s++)
                    af[i][s] = *(const bf16x8*)(Asb + (((mb + i * 16) * 8 + ((q + 4 * s) ^ swz)) * 8));
#pragma unroll
            for (int j = 0; j < NJ; j++)
#pragma unroll
                for (int s = 0; s < 2; s++)
                    bfr[j][s] = *(const bf16x8*)(Bsb + (((nb + j * 16) * 8 + ((q + 4 * s) ^ swz)) * 8));
#pragma unroll
            for (int i = 0; i < 4; i++)
#pragma unroll
                for (int j = 0; j < NJ; j++) {
                    acc[i][j] = __builtin_amdgcn_mfma_f32_16x16x32_bf16(af[i][0], bfr[j][0], acc[i][j], 0, 0, 0);
                    acc[i][j] = __builtin_amdgcn_mfma_f32_16x16x32_bf16(af[i][1], bfr[j][1], acc[i][j], 0, 0, 0);
                }
        }
    }
    float pa = prelu[0];
    int r0w = (lane >> 4) * 4;
    int cc = lane & 15;
    if (GATE) {
        float w3[NJ], bvj[NJ];
#pragma unroll
        for (int j = 0; j < NJ; j++) {
            int col = n0 + wn * (NJ * 16) + j * 16 + cc;
            w3[j] = gW3[col];
            bvj[j] = bias[col];
        }
#pragma unroll
        for (int i = 0; i < 4; i++) {
#pragma unroll
            for (int r = 0; r < 4; r++) {
                float p = 0.f;
#pragma unroll
                for (int j = 0; j < NJ; j++) {
                    float v = acc[i][j][r] * scale + bvj[j];
                    v = (v >= 0.f) ? v : pa * v;
                    p += v * w3[j];
                }
                // reduce across the 16 cc-lanes (masks < 16 stay within the q-group)
                p += __shfl_xor(p, 1, 64); p += __shfl_xor(p, 2, 64);
                p += __shfl_xor(p, 4, 64); p += __shfl_xor(p, 8, 64);
                if (cc == 0) {
                    int row = m0 + wm * 64 + i * 16 + r0w + r;
                    atomicAdd(&gateOut[row], p);
                }
            }
        }
        return;
    }
#pragma unroll
    for (int j = 0; j < NJ; j++) {
        int col = n0 + wn * (NJ * 16) + j * 16 + cc;
        float bv = bias[col];
#pragma unroll
        for (int i = 0; i < 4; i++) {
#pragma unroll
            for (int r = 0; r < 4; r++) {
                int row = m0 + wm * 64 + i * 16 + r0w + r;
                float v = acc[i][j][r] * scale + bv;
                v = (v >= 0.f) ? v : pa * v;
                if (f32out) ((float*)Cout)[(size_t)row * N + col] = v;
                else        ((u16*)Cout)[(size_t)row * N + col] = f2b(v);
            }
        }
    }
}

// distinct wrapper names so rocprof attributes each GEMM separately
__global__ __launch_bounds__(256, 2) void k_gemm_big(
        const u16* __restrict__ A, const u16* __restrict__ Bt, void* __restrict__ Cout,
        const float* __restrict__ bias, const float* __restrict__ prelu, float scale,
        int N, int K) {
    gemm_body<128, 1, 0>(A, Bt, Cout, bias, prelu, scale, N, K, 0, nullptr, nullptr);
}
__global__ __launch_bounds__(256, 2) void k_gemm_l1(
        const u16* __restrict__ A, const u16* __restrict__ Bt, void* __restrict__ Cout,
        const float* __restrict__ bias, const float* __restrict__ prelu, float scale,
        int N, int K) {
    gemm_body<64, 2, 0>(A, Bt, Cout, bias, prelu, scale, N, K, 0, nullptr, nullptr);
}
__global__ __launch_bounds__(256, 2) void k_gemm_g1(
        const u16* __restrict__ A, const u16* __restrict__ Bt, void* __restrict__ Cout,
        const float* __restrict__ bias, const float* __restrict__ prelu, float scale,
        int N, int K) {
    gemm_body<64, 2, 0>(A, Bt, Cout, bias, prelu, scale, N, K, 0, nullptr, nullptr);
}
__global__ __launch_bounds__(256, 2) void k_gemm_g2(
        const u16* __restrict__ A, const u16* __restrict__ Bt,
        const float* __restrict__ bias, const float* __restrict__ prelu,
        int N, int K, const float* __restrict__ gW3, float* __restrict__ gateOut) {
    gemm_body<64, 2, 1>(A, Bt, nullptr, bias, prelu, 1.0f, N, K, 0, gW3, gateOut);
}

// ---------------- pooling ----------------
// grid (64,3): C2D split across grid.y; ushort4 h2 loads, float4 stores.
__global__ void k_pool(const float* __restrict__ gate, const u16* __restrict__ h2,
                       const int* __restrict__ batch, float* __restrict__ out) {
    int b = blockIdx.x, t = threadIdx.x;
    int c = blockIdx.y * 1024 + t * 4;
    int lo = lower_bound(batch, N_NODES, b);
    int hi = lower_bound(batch, N_NODES, b + 1);
    int cnt = hi - lo;
    if (cnt <= 0) {
        float4 z; z.x = z.y = z.z = z.w = 0.f;
        *(float4*)(out + (size_t)b * C2D + c) = z;
        return;
    }
    if (cnt > 256) cnt = 256;   // multinomial(4096,1/64) max ~110; safety clamp
    __shared__ float w[256];
    __shared__ float red[4];
    int lane = t & 63, wv = t >> 6;
    float mx = -1e30f;
    for (int i = t; i < cnt; i += 256) mx = fmaxf(mx, gate[lo + i]);
    mx = wmax(mx);
    if (lane == 0) red[wv] = mx;
    __syncthreads();
    mx = fmaxf(fmaxf(red[0], red[1]), fmaxf(red[2], red[3]));
    __syncthreads();
    float ds = 0.f;
    for (int i = t; i < cnt; i += 256) { float e = __expf(gate[lo + i] - mx); w[i] = e; ds += e; }
    ds = wsum(ds);
    if (lane == 0) red[wv] = ds;
    __syncthreads();
    float inv = 1.0f / (red[0] + red[1] + red[2] + red[3] + 1e-16f);
    float4 acc; acc.x = acc.y = acc.z = acc.w = 0.f;
    const u16* hp = h2 + (size_t)lo * C2D + c;
    for (int i = 0; i < cnt; i++) {
        ushort4 hv = *(const ushort4*)hp; hp += C2D;
        float wi = w[i];
        acc.x += wi * b2f(hv.x); acc.y += wi * b2f(hv.y);
        acc.z += wi * b2f(hv.z); acc.w += wi * b2f(hv.w);
    }
    acc.x *= inv; acc.y *= inv; acc.z *= inv; acc.w *= inv;
    *(float4*)(out + (size_t)b * C2D + c) = acc;
}

// ---------------- launch ----------------
extern "C" void kernel_launch(void* const* d_in, const int* in_sizes, int n_in,
                              void* d_out, int out_size, void* d_ws, size_t ws_size,
                              hipStream_t stream) {
    (void)in_sizes; (void)n_in; (void)out_size;
    const float* x      = (const float*)d_in[0];
    const int*   eidx   = (const int*)d_in[1];
    const float* eattr  = (const float*)d_in[2];
    const int*   batch  = (const int*)d_in[3];
    const float* W1     = (const float*)d_in[4];
    const float* att_s1 = (const float*)d_in[5];
    const float* att_d1 = (const float*)d_in[6];
    const float* We1    = (const float*)d_in[7];
    const float* att_e1 = (const float*)d_in[8];
    const float* bias1  = (const float*)d_in[9];
    const float* prelu1 = (const float*)d_in[10];
    const float* W2     = (const float*)d_in[11];
    const float* att_s2 = (const float*)d_in[12];
    const float* att_d2 = (const float*)d_in[13];
    const float* We2    = (const float*)d_in[14];
    const float* att_e2 = (const float*)d_in[15];
    const float* bias2  = (const float*)d_in[16];
    const float* prelu2 = (const float*)d_in[17];
    const float* gW1    = (const float*)d_in[18];
    const float* gb1    = (const float*)d_in[19];
    const float* ga1    = (const float*)d_in[20];
    const float* gW2    = (const float*)d_in[21];
    const float* gb2    = (const float*)d_in[22];
    const float* ga2    = (const float*)d_in[23];
    const float* gW3    = (const float*)d_in[24];
    const int* srcA = eidx;
    const int* dstA = eidx + N_EDGES;

    // ---- workspace
    char* wp = (char*)d_ws;
    auto alloc = [&](size_t bytes) -> void* {
        void* p = (void*)wp; wp += (bytes + 255) & ~(size_t)255; return p;
    };
    int*   deg  = (int*)alloc(N_NODES * 4);
    int*   cur  = (int*)alloc(N_NODES * 4);
    int*   offs = (int*)alloc((N_NODES + 1) * 4);
    int*   csr  = (int*)alloc(EA_EDGES * 4);
    float* vsd1 = (float*)alloc(CLIPD * 8 * 4);
    float* we12 = (float*)alloc(CLIPD * 8 * 4);
    float* vsd2 = (float*)alloc(HIDD * 8 * 4);
    float* ae   = (float*)alloc((size_t)N_EDGES * 8 * 4);   // real edges only (self-loop in-kernel)
    float* asd1 = (float*)alloc((size_t)N_NODES * 8 * 4);
    float* asd2 = (float*)alloc((size_t)N_NODES * 8 * 4);
    float* gate = (float*)alloc(N_NODES * 4);
    // union 1 (33.6MB): agg1 [N,3072]bf16 / agg2 [N,4096]bf16
    char*  aggU = (char*)alloc((size_t)N_NODES * 4096 * 2);
    u16*   agg1 = (u16*)aggU;
    u16*   agg2 = (u16*)aggU;
    // union 2 (8.4MB): h1 / g1 (h1 dead before g1 written)
    u16*   h1   = (u16*)alloc((size_t)N_NODES * HIDD * 2);
    u16*   g1   = h1;
    u16*   h2   = (u16*)alloc((size_t)N_NODES * C2D * 2);          // 25.2MB
    // transpose outputs: fused single-dispatch path needs all four live (~40MB);
    // fall back to a shared sequential buffer if workspace is tight.
    size_t used = (size_t)(wp - (char*)d_ws);
    bool fused_tr = (ws_size == 0) || (ws_size > used + (size_t)42 * 1024 * 1024);
    u16 *W1t, *W2t, *gW1t, *gW2t;
    if (fused_tr) {
        W1t  = (u16*)alloc((size_t)1024 * 3072 * 2);
        W2t  = (u16*)alloc((size_t)3072 * 4096 * 2);
        gW1t = (u16*)alloc((size_t)1024 * 3072 * 2);
        gW2t = (u16*)alloc((size_t)1024 * 1024 * 2);
    } else {
        u16* Btb = (u16*)alloc((size_t)C2D * 4096 * 2);
        W1t = W2t = gW1t = gW2t = Btb;
    }

    hipMemsetAsync(deg, 0, N_NODES * 4, stream);
    hipMemsetAsync(cur, 0, N_NODES * 4, stream);
    hipMemsetAsync(gate, 0, N_NODES * 4, stream);
    if (fused_tr) {
        hipMemsetAsync(vsd1, 0, CLIPD * 8 * 4, stream);   // accumulated via atomics in transpose
        hipMemsetAsync(vsd2, 0, HIDD * 8 * 4, stream);
    }

    // CSR by dst (includes self loops)
    k_deg<<<(N_EDGES + 255) / 256, 256, 0, stream>>>(dstA, deg);
    k_scan<<<1, 1024, 0, stream>>>(deg, offs);
    k_fill<<<(EA_EDGES + 255) / 256, 256, 0, stream>>>(dstA, offs, cur, csr);

    // weight-side reductions + weight transposes (input-only deps, front-loaded).
    // fused path: W1/W2 reductions ride the transpose pass (one read of W1/W2 total).
    if (fused_tr) {
        k_reduce_we<<<2 * CLIPD, 256, 0, stream>>>(We1, att_e1, We2, att_e2, we12);
        k_transpose_red_all<<<4864, dim3(64, 4), 0, stream>>>(
            W1, W1t, att_s1, att_d1, vsd1, W2, W2t, att_s2, att_d2, vsd2,
            gW1, gW1t, gW2, gW2t);
    } else {
        k_reduce_all<<<2 * CLIPD + HIDD + CLIPD, 256, 0, stream>>>(
            W1, att_s1, att_d1, vsd1, We1, att_e1, W2, att_s2, att_d2, vsd2, We2, att_e2, we12);
    }

    // edge attention logits (both layers) + node src/dst logits for layer 1, fused
    k_gemv8_dual<<<(N_EDGES + N_NODES) / 4, 256, 0, stream>>>(
        eattr, we12, ae, N_EDGES, x, vsd1, asd1);

    // ---- layer 1: aggregate in input space, then one fused GEMM (head-mean=0.25, bias, prelu)
    k_attn_agg<float><<<N_NODES, 256, 0, stream>>>(x, CLIPD, asd1, ae, 0, offs, csr, srcA, agg1);
    if (!fused_tr)
        k_transpose<<<dim3(HIDD / 64, C2D / 64), dim3(64, 4), 0, stream>>>(W1, W1t, C2D, HIDD);
    k_gemm_l1<<<dim3(HIDD / 64, N_NODES / 128), 256, 0, stream>>>(
        agg1, W1t, h1, bias1, prelu1, 0.25f, HIDD, C2D);

    // ---- layer 2
    k_gemv8<u16><<<N_NODES / 4, 256, 0, stream>>>(h1, HIDD, vsd2, asd2, N_NODES);
    k_attn_agg<u16><<<N_NODES, 256, 0, stream>>>(h1, HIDD, asd2, ae, 4, offs, csr, srcA, agg2);
    if (!fused_tr)
        k_transpose<<<dim3(C2D / 64, 4096 / 64), dim3(64, 4), 0, stream>>>(W2, W2t, 4096, C2D);
    k_gemm_big<<<dim3(C2D / 128, N_NODES / 128), 256, 0, stream>>>(
        agg2, W2t, h2, bias2, prelu2, 0.25f, C2D, 4096);

    // ---- gate MLP; final linear+gb3 folded into gate-2 GEMM epilogue (softmax shift-invariant)
    if (!fused_tr)
        k_transpose<<<dim3(HIDD / 64, C2D / 64), dim3(64, 4), 0, stream>>>(gW1, gW1t, C2D, HIDD);
    k_gemm_g1<<<dim3(HIDD / 64, N_NODES / 128), 256, 0, stream>>>(
        h2, gW1t, g1, gb1, ga1, 1.0f, HIDD, C2D);
    if (!fused_tr)
        k_transpose<<<dim3(HIDD / 64, HIDD / 64), dim3(64, 4), 0, stream>>>(gW2, gW2t, HIDD, HIDD);
    k_gemm_g2<<<dim3(HIDD / 64, N_NODES / 128), 256, 0, stream>>>(
        g1, gW2t, gb2, ga2, HIDD, HIDD, gW3, gate);

    // ---- attentional pooling over sorted batch (fp32 output)
    k_pool<<<dim3(NBATCH, 3), 256, 0, stream>>>(gate, h2, batch, (float*)d_out);
}

// Round 6
// 530.622 us; speedup vs baseline: 1.1441x; 1.1441x over previous
//
#include <hip/hip_runtime.h>
#include <stdint.h>
#include <stddef.h>

// ---------------- problem constants ----------------
#define N_NODES  4096
#define N_EDGES  12288
#define EA_EDGES 16384      // N_EDGES + N_NODES self loops
#define NBATCH   64
#define CLIPD    768
#define HIDD     1024
#define C2D      3072
#define NEG_SLOPE 0.2f
#define MAXDEG   96         // in-degree ~Poisson(3); P(>96) ~ 0

typedef unsigned short u16;
typedef short bf16x8 __attribute__((ext_vector_type(8)));   // 8 bf16 = 4 VGPRs (guide §3)
typedef float f32x4  __attribute__((ext_vector_type(4)));

static __device__ __forceinline__ float b2f(u16 u) {
    union { float f; unsigned int i; } v; v.i = ((unsigned int)u) << 16; return v.f;
}
static __device__ __forceinline__ u16 f2b(float f) {
    union { float f; unsigned int i; } v; v.f = f;
    unsigned int r = (v.i + 0x7fffu + ((v.i >> 16) & 1u)) >> 16;   // RNE
    return (u16)r;
}
// dtype-polymorphic 4-element vector load (fp32 or bf16 source) -> 4 floats
static __device__ __forceinline__ void ld4(const float* p, float v[4]) {
    float4 t = *(const float4*)p;
    v[0] = t.x; v[1] = t.y; v[2] = t.z; v[3] = t.w;
}
static __device__ __forceinline__ void ld4(const u16* p, float v[4]) {
    ushort4 t = *(const ushort4*)p;
    v[0] = b2f(t.x); v[1] = b2f(t.y); v[2] = b2f(t.z); v[3] = b2f(t.w);
}

static __device__ __forceinline__ float wsum(float v) {
#pragma unroll
    for (int o = 32; o > 0; o >>= 1) v += __shfl_xor(v, o, 64);
    return v;
}
static __device__ __forceinline__ float wmax(float v) {
#pragma unroll
    for (int o = 32; o > 0; o >>= 1) v = fmaxf(v, __shfl_xor(v, o, 64));
    return v;
}
static __device__ __forceinline__ int lower_bound(const int* a, int n, int key) {
    int lo = 0, hi = n;
    while (lo < hi) { int m = (lo + hi) >> 1; if (a[m] < key) lo = m + 1; else hi = m; }
    return lo;
}

// async global->LDS, 16B per lane. LDS dst is wave-uniform base + lane*16 (m104/m108);
// our LDS offsets are exactly tid*16, satisfying that constraint.
#define GLD16(gp, lp)                                                            \
    __builtin_amdgcn_global_load_lds((const __attribute__((address_space(1))) void*)(gp), \
                                     (__attribute__((address_space(3))) void*)(lp), 16, 0, 0)

// ---------------- CSR build ----------------
__global__ void k_deg(const int* __restrict__ dst, int* __restrict__ deg) {
    int e = blockIdx.x * 256 + threadIdx.x;
    if (e < N_EDGES) atomicAdd(&deg[dst[e]], 1);
}

__global__ void k_scan(const int* __restrict__ deg, int* __restrict__ offs) {
    __shared__ int s[1024];
    int t = threadIdx.x;
    int v[4]; int sum = 0;
#pragma unroll
    for (int i = 0; i < 4; i++) { v[i] = deg[t * 4 + i] + 1; sum += v[i]; }
    s[t] = sum; __syncthreads();
    for (int st = 1; st < 1024; st <<= 1) {
        int x = 0;
        if (t >= st) x = s[t - st];
        __syncthreads();
        s[t] += x;
        __syncthreads();
    }
    int run = s[t] - sum;
#pragma unroll
    for (int i = 0; i < 4; i++) { offs[t * 4 + i] = run; run += v[i]; }
    if (t == 1023) offs[N_NODES] = run;
}

__global__ void k_fill(const int* __restrict__ dst, const int* __restrict__ offs,
                       int* __restrict__ cur, int* __restrict__ csr) {
    int id = blockIdx.x * 256 + threadIdx.x;
    if (id >= EA_EDGES) return;
    int d = (id < N_EDGES) ? dst[id] : (id - N_EDGES);
    int p = atomicAdd(&cur[d], 1);
    csr[offs[d] + p] = id;
}

// ---------------- weight-side attention reductions (fp32 in, fp32 out) ----------------
// R6: back to the dedicated full-BW reduction kernel (R5's in-transpose wsum fusion
// regressed 80 us: 12-step shuffle chains serialized the load loop -- G5/G7).
static __device__ void reduce_w_body(const float* __restrict__ W, const float* __restrict__ attA,
                                     const float* __restrict__ attB, float* __restrict__ out,
                                     int C, int col0, int d) {
    int t = threadIdx.x;
    float acc[8] = {0, 0, 0, 0, 0, 0, 0, 0};
    for (int c = t * 4; c < C; c += 1024) {
#pragma unroll
        for (int h = 0; h < 4; h++) {
            float4 w = *(const float4*)&W[((size_t)d * 4 + h) * C + c];
            float4 a = *(const float4*)&attA[h * C + c];
            acc[h] += w.x * a.x + w.y * a.y + w.z * a.z + w.w * a.w;
            if (attB) {
                float4 bv = *(const float4*)&attB[h * C + c];
                acc[4 + h] += w.x * bv.x + w.y * bv.y + w.z * bv.z + w.w * bv.w;
            }
        }
    }
    __shared__ float red[4][8];
    int lane = t & 63, wv = t >> 6;
#pragma unroll
    for (int j = 0; j < 8; j++) acc[j] = wsum(acc[j]);
    if (lane == 0) {
#pragma unroll
        for (int j = 0; j < 8; j++) red[wv][j] = acc[j];
    }
    __syncthreads();
    if (t < 8) {
        float s = red[0][t] + red[1][t] + red[2][t] + red[3][t];
        if (attB) out[d * 8 + col0 + t] = s;
        else if (t < 4) out[d * 8 + col0 + t] = s;
    }
}

__global__ void k_reduce_all(const float* __restrict__ W1, const float* __restrict__ as1,
                             const float* __restrict__ ad1, float* __restrict__ vsd1,
                             const float* __restrict__ We1, const float* __restrict__ ae1,
                             const float* __restrict__ W2, const float* __restrict__ as2,
                             const float* __restrict__ ad2, float* __restrict__ vsd2,
                             const float* __restrict__ We2, const float* __restrict__ ae2,
                             float* __restrict__ we12) {
    int b = blockIdx.x;
    if (b < CLIPD)                   reduce_w_body(W1, as1, ad1, vsd1, HIDD, 0, b);
    else if (b < 2 * CLIPD)          reduce_w_body(We1, ae1, nullptr, we12, HIDD, 0, b - CLIPD);
    else if (b < 2 * CLIPD + HIDD)   reduce_w_body(W2, as2, ad2, vsd2, C2D, 0, b - 2 * CLIPD);
    else                             reduce_w_body(We2, ae2, nullptr, we12, C2D, 4, b - 2 * CLIPD - HIDD);
}

// skinny GEMV: out[row][0..7] = X[row,:] @ Wr[:,0..7]   (one wave per row, 4-wide k)
template <typename T>
static __device__ void gemv8_body(const T* __restrict__ X, int K, const float* __restrict__ Wr,
                                  float* __restrict__ out, int row) {
    int lane = threadIdx.x & 63;
    float acc[8] = {0, 0, 0, 0, 0, 0, 0, 0};
    const T* xp = X + (size_t)row * K;
    for (int k = lane * 4; k < K; k += 256) {
        float xv[4]; ld4(xp + k, xv);
#pragma unroll
        for (int kk = 0; kk < 4; kk++) {
            const float4* w = (const float4*)(Wr + (size_t)(k + kk) * 8);
            float4 w0 = w[0], w1 = w[1];
            acc[0] += xv[kk] * w0.x; acc[1] += xv[kk] * w0.y;
            acc[2] += xv[kk] * w0.z; acc[3] += xv[kk] * w0.w;
            acc[4] += xv[kk] * w1.x; acc[5] += xv[kk] * w1.y;
            acc[6] += xv[kk] * w1.z; acc[7] += xv[kk] * w1.w;
        }
    }
#pragma unroll
    for (int j = 0; j < 8; j++) acc[j] = wsum(acc[j]);
    if (lane == 0) {
#pragma unroll
        for (int j = 0; j < 8; j++) out[(size_t)row * 8 + j] = acc[j];
    }
}

template <typename T>
__global__ void k_gemv8(const T* __restrict__ X, int K, const float* __restrict__ Wr,
                        float* __restrict__ out, int rows) {
    int row = blockIdx.x * 4 + (threadIdx.x >> 6);
    if (row < rows) gemv8_body(X, K, Wr, out, row);
}

// fused dual gemv (eattr->ae and x->asd1 are independent; one dispatch)
__global__ void k_gemv8_dual(const float* __restrict__ Xa, const float* __restrict__ Wa,
                             float* __restrict__ outA, int rowsA,
                             const float* __restrict__ Xb, const float* __restrict__ Wb,
                             float* __restrict__ outB) {
    int row = blockIdx.x * 4 + (threadIdx.x >> 6);
    if (row < rowsA) gemv8_body(Xa, CLIPD, Wa, outA, row);
    else             gemv8_body(Xb, CLIPD, Wb, outB, row - rowsA);
}

// per-dst-node attention softmax + aggregation in INPUT feature space:
// agg[n, d*4+h] = sum_e coef[e,h] * feat[src_e, d]
// self-loop logit computed in-kernel (mean of incident real edges' raw ae component).
template <typename T>
__global__ void k_attn_agg(const T* __restrict__ feat, int D,
                           const float* __restrict__ asd, const float* __restrict__ ae, int aecol,
                           const int* __restrict__ offs, const int* __restrict__ csr,
                           const int* __restrict__ src, u16* __restrict__ agg) {
    int n = blockIdx.x, t = threadIdx.x;
    __shared__ int sl[MAXDEG];
    __shared__ float cf[MAXDEG][4];
    __shared__ float er[MAXDEG][4];   // raw edge-attn component (0 for self-loop slot)
    __shared__ int sidx;
    if (t == 0) sidx = -1;
    int lo = offs[n];
    int cnt = offs[n + 1] - lo;
    if (cnt > MAXDEG) cnt = MAXDEG;
    __syncthreads();
    for (int i = t; i < cnt; i += 256) {
        int eid = csr[lo + i];
        bool slf = (eid >= N_EDGES);
        int s = slf ? n : src[eid];
        sl[i] = s;
        if (slf) sidx = i;
#pragma unroll
        for (int h = 0; h < 4; h++) {
            float aev = slf ? 0.f : ae[(size_t)eid * 8 + aecol + h];
            er[i][h] = aev;
            float al = asd[(size_t)s * 8 + h] + asd[(size_t)n * 8 + 4 + h] + aev;
            cf[i][h] = (al >= 0.f) ? al : NEG_SLOPE * al;
        }
    }
    __syncthreads();
    int wv = t >> 6, lane = t & 63;
    {   // self-loop logit: head wv, wave-parallel mean of real-edge ae
        float se = 0.f;
        for (int i = lane; i < cnt; i += 64) se += er[i][wv];
        se = wsum(se);
        if (lane == 0 && sidx >= 0) {
            float al = asd[(size_t)n * 8 + wv] + asd[(size_t)n * 8 + 4 + wv] +
                       se / (float)(cnt > 1 ? cnt - 1 : 1);
            cf[sidx][wv] = (al >= 0.f) ? al : NEG_SLOPE * al;
        }
    }
    __syncthreads();
    {   // head = wave index: all 4 waves active, shuffle-reduce softmax
        float mx = -1e30f;
        for (int i = lane; i < cnt; i += 64) mx = fmaxf(mx, cf[i][wv]);
        mx = wmax(mx);
        float ds = 0.f;
        for (int i = lane; i < cnt; i += 64) {
            float e = __expf(cf[i][wv] - mx); cf[i][wv] = e; ds += e;
        }
        ds = wsum(ds);
        float inv = 1.0f / (ds + 1e-16f);
        for (int i = lane; i < cnt; i += 64) cf[i][wv] *= inv;
    }
    __syncthreads();
    for (int d4 = t * 4; d4 < D; d4 += 1024) {
        float a[4][4] = {};                     // [dj][head]
        for (int i = 0; i < cnt; i++) {
            float4 c4 = *(const float4*)cf[i];  // 4 heads, LDS broadcast
            float v[4]; ld4(feat + (size_t)sl[i] * D + d4, v);
#pragma unroll
            for (int dj = 0; dj < 4; dj++) {
                a[dj][0] += c4.x * v[dj]; a[dj][1] += c4.y * v[dj];
                a[dj][2] += c4.z * v[dj]; a[dj][3] += c4.w * v[dj];
            }
        }
        u16* op = agg + (size_t)n * 4 * D + (size_t)d4 * 4;
#pragma unroll
        for (int dj = 0; dj < 4; dj++) {
            ushort4 pk;
            pk.x = f2b(a[dj][0]); pk.y = f2b(a[dj][1]);
            pk.z = f2b(a[dj][2]); pk.w = f2b(a[dj][3]);
            *(ushort4*)(op + dj * 4) = pk;
        }
    }
}

// ---------------- transpose + downcast (fp32 [R,C] -> bf16 [C,R]) ----------------
// ushort4 stores; LDS read tile[s4+k][j]: bank = (4*(s4+k)+j)%32 covers all residues 2x = free.
static __device__ void transpose_body(const float* __restrict__ in, u16* __restrict__ out,
                                      int R, int C, int bx, int by) {
    __shared__ float tile[64][65];
    int tx = threadIdx.x, ty = threadIdx.y;
    int rb = by * 64, cb = bx * 64;
    for (int i = ty; i < 64; i += 4) tile[i][tx] = in[(size_t)(rb + i) * C + cb + tx];
    __syncthreads();
    int linear = ty * 64 + tx;
#pragma unroll
    for (int jj = 0; jj < 4; jj++) {
        int idx = linear + jj * 256;
        int j = idx >> 4, s4 = (idx & 15) * 4;
        ushort4 pk;
        pk.x = f2b(tile[s4 + 0][j]);
        pk.y = f2b(tile[s4 + 1][j]);
        pk.z = f2b(tile[s4 + 2][j]);
        pk.w = f2b(tile[s4 + 3][j]);
        *(ushort4*)(out + (size_t)(cb + j) * R + rb + s4) = pk;
    }
}

__global__ void k_transpose(const float* __restrict__ in, u16* __restrict__ out, int R, int C) {
    transpose_body(in, out, R, C, blockIdx.x, blockIdx.y);
}

// all four weight transposes in ONE dispatch (plain -- no fused reduction, per R5 lesson).
// tiles: W1 [3072,1024]=768, W2 [4096,3072]=3072, gW1 [3072,1024]=768, gW2 [1024,1024]=256.
__global__ void k_transpose_all(const float* __restrict__ W1, u16* __restrict__ W1t,
                                const float* __restrict__ W2, u16* __restrict__ W2t,
                                const float* __restrict__ gW1, u16* __restrict__ gW1t,
                                const float* __restrict__ gW2, u16* __restrict__ gW2t) {
    int b = blockIdx.x;
    const float* in; u16* out; int R, C, lb, txc;
    if (b < 768)       { in = W1;  out = W1t;  R = 3072; C = 1024; lb = b;        txc = 16; }
    else if (b < 3840) { in = W2;  out = W2t;  R = 4096; C = 3072; lb = b - 768;  txc = 48; }
    else if (b < 4608) { in = gW1; out = gW1t; R = 3072; C = 1024; lb = b - 3840; txc = 16; }
    else               { in = gW2; out = gW2t; R = 1024; C = 1024; lb = b - 4608; txc = 16; }
    transpose_body(in, out, R, C, lb % txc, lb / txc);
}

// ---------------- MFMA GEMM: C = prelu(scale * A@Bt^T + bias) ----------------
// A [M,K] bf16 row-major, Bt [N,K] bf16 row-major. 128xBN tile, 4 waves, KSUB
// 64-wide k-subtiles per barrier pair.
// Measured tile-space for THIS structure (R3-R5): big @BN=128/KSUB=1 = 110us;
// @BN=256 = 130us (1.5 blocks/CU -> no co-resident block covers the
// vmcnt(0)+barrier drain, m114). Keep >=2 blocks/CU.
// R6: keep R4's j-outer b0/b1-preload inner loop (R4 evidence: small GEMMs -20us).
// GATE mode: dot-reduce prelu(C) against gW3, atomicAdd into gate[row].
template <int BN, int KSUB, int GATE>
static __device__ __forceinline__ void gemm_body(
        const u16* __restrict__ A, const u16* __restrict__ Bt, void* __restrict__ Cout,
        const float* __restrict__ bias, const float* __restrict__ prelu, float scale,
        int N, int K, int f32out,
        const float* __restrict__ gW3, float* __restrict__ gateOut) {
    constexpr int NJ = BN / 32;              // 16-wide n-subtiles per wave (2 waves along N)
    constexpr int NBCH = BN * 8 / 256;       // B chunks per thread per subtile
    __shared__ __align__(16) u16 As[KSUB * 128 * 64];
    __shared__ __align__(16) u16 Bs[KSUB * BN * 64];
    int tid = threadIdx.x;
    int lane = tid & 63, wv = tid >> 6;
    int gx = gridDim.x;
    int bx = blockIdx.x, by = blockIdx.y;
    if ((gx & 7) == 0) {                     // bijective when gx%8==0
        int flat = by * gx + bx;
        int nx_per = gx >> 3;
        int xcd = flat & 7, idx = flat >> 3;
        bx = xcd * nx_per + idx % nx_per;
        by = idx / nx_per;
    }
    int m0 = by * 128, n0 = bx * BN;
    const u16* agp[4]; int alo[4];
#pragma unroll
    for (int u = 0; u < 4; u++) {
        int c = tid + u * 256;
        int r = c >> 3, kb = (c & 7) ^ (r & 7);
        agp[u] = A + (size_t)(m0 + r) * K + kb * 8;
        alo[u] = c * 8;
    }
    const u16* bgp[NBCH]; int blo[NBCH];
#pragma unroll
    for (int u = 0; u < NBCH; u++) {
        int c = tid + u * 256;
        int r = c >> 3, kb = (c & 7) ^ (r & 7);
        bgp[u] = Bt + (size_t)(n0 + r) * K + kb * 8;
        blo[u] = c * 8;
    }
    int wm = wv & 1, wn = wv >> 1;
    int rl = lane & 15, q = lane >> 4;
    int swz = rl & 7;
    int mb = wm * 64 + rl;
    int nb = wn * (NJ * 16) + rl;
    f32x4 acc[4][NJ] = {};
    for (int k0 = 0; k0 < K; k0 += 64 * KSUB) {
        __syncthreads();                       // previous tile's LDS reads done
#pragma unroll
        for (int su = 0; su < KSUB; su++) {
#pragma unroll
            for (int u = 0; u < 4; u++)    GLD16(agp[u] + su * 64, As + su * (128 * 64) + alo[u]);
#pragma unroll
            for (int u = 0; u < NBCH; u++) GLD16(bgp[u] + su * 64, Bs + su * (BN * 64) + blo[u]);
        }
#pragma unroll
        for (int u = 0; u < 4; u++)    agp[u] += 64 * KSUB;
#pragma unroll
        for (int u = 0; u < NBCH; u++) bgp[u] += 64 * KSUB;
        __syncthreads();                       // drains vmcnt(0): staging landed
#pragma unroll
        for (int su = 0; su < KSUB; su++) {
            const u16* Asb = As + su * (128 * 64);
            const u16* Bsb = Bs + su * (BN * 64);
            bf16x8 af[4][2];
#pragma unroll
            for (int i = 0; i < 4; i++)
#pragma unroll
                for (int s = 0; s < 2; s++)
                    af[i][s] = *(const bf16x8*)(Asb + (((mb + i * 16) * 8 + ((q + 4 * s) ^ swz)) * 8));
#pragma unroll
            for (int j = 0; j < NJ; j++) {
                bf16x8 b0 = *(const bf16x8*)(Bsb + (((nb + j * 16) * 8 + ((q + 4 * 0) ^ swz)) * 8));
                bf16x8 b1 = *(const bf16x8*)(Bsb + (((nb + j * 16) * 8 + ((q + 4 * 1) ^ swz)) * 8));
#pragma unroll
                for (int i = 0; i < 4; i++) {
                    acc[i][j] = __builtin_amdgcn_mfma_f32_16x16x32_bf16(af[i][0], b0, acc[i][j], 0, 0, 0);
                    acc[i][j] = __builtin_amdgcn_mfma_f32_16x16x32_bf16(af[i][1], b1, acc[i][j], 0, 0, 0);
                }
            }
        }
    }
    float pa = prelu[0];
    int r0w = (lane >> 4) * 4;
    int cc = lane & 15;
    if (GATE) {
        float w3[NJ], bvj[NJ];
#pragma unroll
        for (int j = 0; j < NJ; j++) {
            int col = n0 + wn * (NJ * 16) + j * 16 + cc;
            w3[j] = gW3[col];
            bvj[j] = bias[col];
        }
#pragma unroll
        for (int i = 0; i < 4; i++) {
#pragma unroll
            for (int r = 0; r < 4; r++) {
                float p = 0.f;
#pragma unroll
                for (int j = 0; j < NJ; j++) {
                    float v = acc[i][j][r] * scale + bvj[j];
                    v = (v >= 0.f) ? v : pa * v;
                    p += v * w3[j];
                }
                // reduce across the 16 cc-lanes (masks < 16 stay within the q-group)
                p += __shfl_xor(p, 1, 64); p += __shfl_xor(p, 2, 64);
                p += __shfl_xor(p, 4, 64); p += __shfl_xor(p, 8, 64);
                if (cc == 0) {
                    int row = m0 + wm * 64 + i * 16 + r0w + r;
                    atomicAdd(&gateOut[row], p);
                }
            }
        }
        return;
    }
#pragma unroll
    for (int j = 0; j < NJ; j++) {
        int col = n0 + wn * (NJ * 16) + j * 16 + cc;
        float bv = bias[col];
#pragma unroll
        for (int i = 0; i < 4; i++) {
#pragma unroll
            for (int r = 0; r < 4; r++) {
                int row = m0 + wm * 64 + i * 16 + r0w + r;
                float v = acc[i][j][r] * scale + bv;
                v = (v >= 0.f) ? v : pa * v;
                if (f32out) ((float*)Cout)[(size_t)row * N + col] = v;
                else        ((u16*)Cout)[(size_t)row * N + col] = f2b(v);
            }
        }
    }
}

// distinct wrapper names so rocprof attributes each GEMM separately
__global__ __launch_bounds__(256, 2) void k_gemm_big(
        const u16* __restrict__ A, const u16* __restrict__ Bt, void* __restrict__ Cout,
        const float* __restrict__ bias, const float* __restrict__ prelu, float scale,
        int N, int K) {
    gemm_body<128, 1, 0>(A, Bt, Cout, bias, prelu, scale, N, K, 0, nullptr, nullptr);
}
__global__ __launch_bounds__(256, 2) void k_gemm_l1(
        const u16* __restrict__ A, const u16* __restrict__ Bt, void* __restrict__ Cout,
        const float* __restrict__ bias, const float* __restrict__ prelu, float scale,
        int N, int K) {
    gemm_body<64, 2, 0>(A, Bt, Cout, bias, prelu, scale, N, K, 0, nullptr, nullptr);
}
__global__ __launch_bounds__(256, 2) void k_gemm_g1(
        const u16* __restrict__ A, const u16* __restrict__ Bt, void* __restrict__ Cout,
        const float* __restrict__ bias, const float* __restrict__ prelu, float scale,
        int N, int K) {
    gemm_body<64, 2, 0>(A, Bt, Cout, bias, prelu, scale, N, K, 0, nullptr, nullptr);
}
__global__ __launch_bounds__(256, 2) void k_gemm_g2(
        const u16* __restrict__ A, const u16* __restrict__ Bt,
        const float* __restrict__ bias, const float* __restrict__ prelu,
        int N, int K, const float* __restrict__ gW3, float* __restrict__ gateOut) {
    gemm_body<64, 2, 1>(A, Bt, nullptr, bias, prelu, 1.0f, N, K, 0, gW3, gateOut);
}

// ---------------- pooling ----------------
// grid (64,3): C2D split across grid.y; ushort4 h2 loads, float4 stores.
__global__ void k_pool(const float* __restrict__ gate, const u16* __restrict__ h2,
                       const int* __restrict__ batch, float* __restrict__ out) {
    int b = blockIdx.x, t = threadIdx.x;
    int c = blockIdx.y * 1024 + t * 4;
    int lo = lower_bound(batch, N_NODES, b);
    int hi = lower_bound(batch, N_NODES, b + 1);
    int cnt = hi - lo;
    if (cnt <= 0) {
        float4 z; z.x = z.y = z.z = z.w = 0.f;
        *(float4*)(out + (size_t)b * C2D + c) = z;
        return;
    }
    if (cnt > 256) cnt = 256;   // multinomial(4096,1/64) max ~110; safety clamp
    __shared__ float w[256];
    __shared__ float red[4];
    int lane = t & 63, wv = t >> 6;
    float mx = -1e30f;
    for (int i = t; i < cnt; i += 256) mx = fmaxf(mx, gate[lo + i]);
    mx = wmax(mx);
    if (lane == 0) red[wv] = mx;
    __syncthreads();
    mx = fmaxf(fmaxf(red[0], red[1]), fmaxf(red[2], red[3]));
    __syncthreads();
    float ds = 0.f;
    for (int i = t; i < cnt; i += 256) { float e = __expf(gate[lo + i] - mx); w[i] = e; ds += e; }
    ds = wsum(ds);
    if (lane == 0) red[wv] = ds;
    __syncthreads();
    float inv = 1.0f / (red[0] + red[1] + red[2] + red[3] + 1e-16f);
    float4 acc; acc.x = acc.y = acc.z = acc.w = 0.f;
    const u16* hp = h2 + (size_t)lo * C2D + c;
    for (int i = 0; i < cnt; i++) {
        ushort4 hv = *(const ushort4*)hp; hp += C2D;
        float wi = w[i];
        acc.x += wi * b2f(hv.x); acc.y += wi * b2f(hv.y);
        acc.z += wi * b2f(hv.z); acc.w += wi * b2f(hv.w);
    }
    acc.x *= inv; acc.y *= inv; acc.z *= inv; acc.w *= inv;
    *(float4*)(out + (size_t)b * C2D + c) = acc;
}

// ---------------- launch ----------------
extern "C" void kernel_launch(void* const* d_in, const int* in_sizes, int n_in,
                              void* d_out, int out_size, void* d_ws, size_t ws_size,
                              hipStream_t stream) {
    (void)in_sizes; (void)n_in; (void)out_size;
    const float* x      = (const float*)d_in[0];
    const int*   eidx   = (const int*)d_in[1];
    const float* eattr  = (const float*)d_in[2];
    const int*   batch  = (const int*)d_in[3];
    const float* W1     = (const float*)d_in[4];
    const float* att_s1 = (const float*)d_in[5];
    const float* att_d1 = (const float*)d_in[6];
    const float* We1    = (const float*)d_in[7];
    const float* att_e1 = (const float*)d_in[8];
    const float* bias1  = (const float*)d_in[9];
    const float* prelu1 = (const float*)d_in[10];
    const float* W2     = (const float*)d_in[11];
    const float* att_s2 = (const float*)d_in[12];
    const float* att_d2 = (const float*)d_in[13];
    const float* We2    = (const float*)d_in[14];
    const float* att_e2 = (const float*)d_in[15];
    const float* bias2  = (const float*)d_in[16];
    const float* prelu2 = (const float*)d_in[17];
    const float* gW1    = (const float*)d_in[18];
    const float* gb1    = (const float*)d_in[19];
    const float* ga1    = (const float*)d_in[20];
    const float* gW2    = (const float*)d_in[21];
    const float* gb2    = (const float*)d_in[22];
    const float* ga2    = (const float*)d_in[23];
    const float* gW3    = (const float*)d_in[24];
    const int* srcA = eidx;
    const int* dstA = eidx + N_EDGES;

    // ---- workspace
    char* wp = (char*)d_ws;
    auto alloc = [&](size_t bytes) -> void* {
        void* p = (void*)wp; wp += (bytes + 255) & ~(size_t)255; return p;
    };
    int*   deg  = (int*)alloc(N_NODES * 4);
    int*   cur  = (int*)alloc(N_NODES * 4);
    int*   offs = (int*)alloc((N_NODES + 1) * 4);
    int*   csr  = (int*)alloc(EA_EDGES * 4);
    float* vsd1 = (float*)alloc(CLIPD * 8 * 4);
    float* we12 = (float*)alloc(CLIPD * 8 * 4);
    float* vsd2 = (float*)alloc(HIDD * 8 * 4);
    float* ae   = (float*)alloc((size_t)N_EDGES * 8 * 4);   // real edges only (self-loop in-kernel)
    float* asd1 = (float*)alloc((size_t)N_NODES * 8 * 4);
    float* asd2 = (float*)alloc((size_t)N_NODES * 8 * 4);
    float* gate = (float*)alloc(N_NODES * 4);
    // union 1 (33.6MB): agg1 [N,3072]bf16 / agg2 [N,4096]bf16
    char*  aggU = (char*)alloc((size_t)N_NODES * 4096 * 2);
    u16*   agg1 = (u16*)aggU;
    u16*   agg2 = (u16*)aggU;
    // union 2 (8.4MB): h1 / g1 (h1 dead before g1 written)
    u16*   h1   = (u16*)alloc((size_t)N_NODES * HIDD * 2);
    u16*   g1   = h1;
    u16*   h2   = (u16*)alloc((size_t)N_NODES * C2D * 2);          // 25.2MB
    // transpose outputs: fused single-dispatch path needs all four live (~40MB);
    // fall back to a shared sequential buffer if workspace is tight.
    size_t used = (size_t)(wp - (char*)d_ws);
    bool fused_tr = (ws_size == 0) || (ws_size > used + (size_t)42 * 1024 * 1024);
    u16 *W1t, *W2t, *gW1t, *gW2t;
    if (fused_tr) {
        W1t  = (u16*)alloc((size_t)1024 * 3072 * 2);
        W2t  = (u16*)alloc((size_t)3072 * 4096 * 2);
        gW1t = (u16*)alloc((size_t)1024 * 3072 * 2);
        gW2t = (u16*)alloc((size_t)1024 * 1024 * 2);
    } else {
        u16* Btb = (u16*)alloc((size_t)C2D * 4096 * 2);
        W1t = W2t = gW1t = gW2t = Btb;
    }

    hipMemsetAsync(deg, 0, N_NODES * 4, stream);
    hipMemsetAsync(cur, 0, N_NODES * 4, stream);
    hipMemsetAsync(gate, 0, N_NODES * 4, stream);

    // CSR by dst (includes self loops)
    k_deg<<<(N_EDGES + 255) / 256, 256, 0, stream>>>(dstA, deg);
    k_scan<<<1, 1024, 0, stream>>>(deg, offs);
    k_fill<<<(EA_EDGES + 255) / 256, 256, 0, stream>>>(dstA, offs, cur, csr);

    // weight-side reductions + all four weight transposes (input-only deps, front-loaded)
    k_reduce_all<<<2 * CLIPD + HIDD + CLIPD, 256, 0, stream>>>(
        W1, att_s1, att_d1, vsd1, We1, att_e1, W2, att_s2, att_d2, vsd2, We2, att_e2, we12);
    if (fused_tr)
        k_transpose_all<<<4864, dim3(64, 4), 0, stream>>>(W1, W1t, W2, W2t, gW1, gW1t, gW2, gW2t);

    // edge attention logits (both layers) + node src/dst logits for layer 1, fused
    k_gemv8_dual<<<(N_EDGES + N_NODES) / 4, 256, 0, stream>>>(
        eattr, we12, ae, N_EDGES, x, vsd1, asd1);

    // ---- layer 1: aggregate in input space, then one fused GEMM (head-mean=0.25, bias, prelu)
    k_attn_agg<float><<<N_NODES, 256, 0, stream>>>(x, CLIPD, asd1, ae, 0, offs, csr, srcA, agg1);
    if (!fused_tr)
        k_transpose<<<dim3(HIDD / 64, C2D / 64), dim3(64, 4), 0, stream>>>(W1, W1t, C2D, HIDD);
    k_gemm_l1<<<dim3(HIDD / 64, N_NODES / 128), 256, 0, stream>>>(
        agg1, W1t, h1, bias1, prelu1, 0.25f, HIDD, C2D);

    // ---- layer 2
    k_gemv8<u16><<<N_NODES / 4, 256, 0, stream>>>(h1, HIDD, vsd2, asd2, N_NODES);
    k_attn_agg<u16><<<N_NODES, 256, 0, stream>>>(h1, HIDD, asd2, ae, 4, offs, csr, srcA, agg2);
    if (!fused_tr)
        k_transpose<<<dim3(C2D / 64, 4096 / 64), dim3(64, 4), 0, stream>>>(W2, W2t, 4096, C2D);
    k_gemm_big<<<dim3(C2D / 128, N_NODES / 128), 256, 0, stream>>>(
        agg2, W2t, h2, bias2, prelu2, 0.25f, C2D, 4096);

    // ---- gate MLP; final linear+gb3 folded into gate-2 GEMM epilogue (softmax shift-invariant)
    if (!fused_tr)
        k_transpose<<<dim3(HIDD / 64, C2D / 64), dim3(64, 4), 0, stream>>>(gW1, gW1t, C2D, HIDD);
    k_gemm_g1<<<dim3(HIDD / 64, N_NODES / 128), 256, 0, stream>>>(
        h2, gW1t, g1, gb1, ga1, 1.0f, HIDD, C2D);
    if (!fused_tr)
        k_transpose<<<dim3(HIDD / 64, HIDD / 64), dim3(64, 4), 0, stream>>>(gW2, gW2t, HIDD, HIDD);
    k_gemm_g2<<<dim3(HIDD / 64, N_NODES / 128), 256, 0, stream>>>(
        g1, gW2t, gb2, ga2, HIDD, HIDD, gW3, gate);

    // ---- attentional pooling over sorted batch (fp32 output)
    k_pool<<<dim3(NBATCH, 3), 256, 0, stream>>>(gate, h2, batch, (float*)d_out);
}